// Round 1
// baseline (976.139 us; speedup 1.0000x reference)
//
#include <hip/hip_runtime.h>

#define E_DIM   256
#define N_CODES 1024
#define BM      128
#define BN      128
#define BK      16
#define LDSS    132   // padded stride: keeps LDS transpose-store conflicts <= 2-way

__global__ __launch_bounds__(256) void vq_kernel(
    const float* __restrict__ z, const float* __restrict__ emb,
    float* __restrict__ zq_out, float* __restrict__ loss_out,
    float* __restrict__ idx_out, int nrows)
{
    __shared__ float At[BK][LDSS];
    __shared__ float Bt[BK][LDSS];
    __shared__ int   rowIdx[BM];
    __shared__ float red[4];

    const int tid = threadIdx.x;
    const int tx  = tid & 15;          // col group (codes)
    const int ty  = tid >> 4;          // row group
    const int rb  = blockIdx.x * BM;   // first row of this block

    float vmax[8];
    int   vidx[8];
#pragma unroll
    for (int r = 0; r < 8; ++r) { vmax[r] = -3.4e38f; vidx[r] = 0; }

    float acc[8][8];

    const int c4   = tid & 3;          // which 4-float chunk of the 16 k's
    const int rrow = tid >> 2;         // 0..63

    for (int cn = 0; cn < N_CODES; cn += BN) {
#pragma unroll
        for (int r = 0; r < 8; ++r)
#pragma unroll
            for (int c = 0; c < 8; ++c) acc[r][c] = 0.f;

        for (int k0 = 0; k0 < E_DIM; k0 += BK) {
            __syncthreads();
            // cooperative load: A tile (z rows) and B tile (emb rows), transposed into LDS
#pragma unroll
            for (int i = 0; i < 2; ++i) {
                const int m = rrow + i * 64;
                const float4 a4 = *reinterpret_cast<const float4*>(
                    &z[(size_t)(rb + m) * E_DIM + k0 + c4 * 4]);
                At[c4 * 4 + 0][m] = a4.x;
                At[c4 * 4 + 1][m] = a4.y;
                At[c4 * 4 + 2][m] = a4.z;
                At[c4 * 4 + 3][m] = a4.w;
                const float4 b4 = *reinterpret_cast<const float4*>(
                    &emb[(size_t)(cn + m) * E_DIM + k0 + c4 * 4]);
                Bt[c4 * 4 + 0][m] = b4.x;
                Bt[c4 * 4 + 1][m] = b4.y;
                Bt[c4 * 4 + 2][m] = b4.z;
                Bt[c4 * 4 + 3][m] = b4.w;
            }
            __syncthreads();

#pragma unroll
            for (int k = 0; k < BK; ++k) {
                float a[8], b[8];
                *reinterpret_cast<float4*>(&a[0]) = *reinterpret_cast<const float4*>(&At[k][ty * 8]);
                *reinterpret_cast<float4*>(&a[4]) = *reinterpret_cast<const float4*>(&At[k][ty * 8 + 4]);
                *reinterpret_cast<float4*>(&b[0]) = *reinterpret_cast<const float4*>(&Bt[k][tx * 8]);
                *reinterpret_cast<float4*>(&b[4]) = *reinterpret_cast<const float4*>(&Bt[k][tx * 8 + 4]);
#pragma unroll
                for (int r = 0; r < 8; ++r)
#pragma unroll
                    for (int c = 0; c < 8; ++c)
                        acc[r][c] = fmaf(a[r], b[c], acc[r][c]);
            }
        }

        // fold this code tile into the running argmax (increasing idx, strict > => first-max)
#pragma unroll
        for (int r = 0; r < 8; ++r) {
#pragma unroll
            for (int c = 0; c < 8; ++c) {
                const int idx = cn + tx * 8 + c;
                if (acc[r][c] > vmax[r]) { vmax[r] = acc[r][c]; vidx[r] = idx; }
            }
        }
    }

    // reduce (max, idx) across the 16 tx lanes of each row group
#pragma unroll
    for (int r = 0; r < 8; ++r) {
        float v = vmax[r];
        int   ix = vidx[r];
#pragma unroll
        for (int s = 1; s < 16; s <<= 1) {
            const float v2 = __shfl_xor(v, s, 64);
            const int   i2 = __shfl_xor(ix, s, 64);
            if (v2 > v || (v2 == v && i2 < ix)) { v = v2; ix = i2; }
        }
        if (tx == 0) rowIdx[ty * 8 + r] = ix;
    }
    __syncthreads();

    // epilogue: gather emb[idx] -> z_q, accumulate SSE, write idx as float
    float sse = 0.f;
#pragma unroll 4
    for (int i = 0; i < 32; ++i) {
        const int f   = i * 256 + tid;   // float4 index within the 128x256 tile
        const int row = f >> 6;          // 64 float4 per row
        const int kq  = f & 63;
        const int idx = rowIdx[row];
        const float4 e4 = *reinterpret_cast<const float4*>(&emb[(size_t)idx * E_DIM + kq * 4]);
        const float4 z4 = *reinterpret_cast<const float4*>(&z[(size_t)(rb + row) * E_DIM + kq * 4]);
        const float dx = e4.x - z4.x, dy = e4.y - z4.y, dz = e4.z - z4.z, dw = e4.w - z4.w;
        sse += dx * dx + dy * dy + dz * dz + dw * dw;
        *reinterpret_cast<float4*>(&zq_out[(size_t)(rb + row) * E_DIM + kq * 4]) = e4;
    }

    if (tid < BM) idx_out[rb + tid] = (float)rowIdx[tid];

    // block-reduce sse, one atomic per block into each loss slot
#pragma unroll
    for (int s = 1; s < 64; s <<= 1) sse += __shfl_xor(sse, s, 64);
    const int wave = tid >> 6, lane = tid & 63;
    if (lane == 0) red[wave] = sse;
    __syncthreads();
    if (tid == 0) {
        const float t   = red[0] + red[1] + red[2] + red[3];
        const float inv = 1.0f / ((float)nrows * (float)E_DIM);
        atomicAdd(&loss_out[0], t * inv);           // vq_loss
        atomicAdd(&loss_out[1], 0.25f * t * inv);   // commitment_loss
    }
}

extern "C" void kernel_launch(void* const* d_in, const int* in_sizes, int n_in,
                              void* d_out, int out_size, void* d_ws, size_t ws_size,
                              hipStream_t stream) {
    const float* z   = (const float*)d_in[0];
    const float* emb = (const float*)d_in[1];
    const int zsz    = in_sizes[0];        // 33554432
    const int nrows  = zsz / E_DIM;        // 131072

    float* out  = (float*)d_out;
    float* zq   = out;                     // [nrows * E_DIM]
    float* loss = out + zsz;               // [2] : vq_loss, commitment_loss
    float* idxf = out + zsz + 2;           // [nrows] as float values

    hipMemsetAsync(loss, 0, 2 * sizeof(float), stream);

    dim3 grid(nrows / BM);
    vq_kernel<<<grid, 256, 0, stream>>>(z, emb, zq, loss, idxf, nrows);
}

// Round 3
// 752.709 us; speedup vs baseline: 1.2968x; 1.2968x over previous
//
#include <hip/hip_runtime.h>

#define E_DIM  256
#define NC     1024
#define BM     128
#define BN     128
#define NT     512
#define LDBS   72       // shorts per LDS B row: 64 data + 8 pad = 144 B
#define MARGIN 0.02f

typedef short  bf16x4 __attribute__((ext_vector_type(4)));
typedef short  bf16x8 __attribute__((ext_vector_type(8)));
typedef float  f32x4  __attribute__((ext_vector_type(4)));

// split f32 into bf16 hi + bf16 lo (both round-to-nearest-even)
static __device__ __forceinline__ void split2(float x, short& hi, short& lo) {
    const unsigned u  = __float_as_uint(x);
    const unsigned hb = (u + 0x7FFFu + ((u >> 16) & 1u)) >> 16;
    hi = (short)hb;
    const float l = x - __uint_as_float(hb << 16);   // exact in f32
    const unsigned u2 = __float_as_uint(l);
    lo = (short)((u2 + 0x7FFFu + ((u2 >> 16) & 1u)) >> 16);
}

// value with low 10 mantissa bits <- (1023 - idx): fmax = value-compare with
// first-index tie-break for positive values; perturbation <=1024 ulp << MARGIN.
static __device__ __forceinline__ float mkey(float v, unsigned il) {
    return __uint_as_float((__float_as_uint(v) & 0xFFFFFC00u) | il);
}

__global__ __launch_bounds__(NT, 2) void vq_kernel(
    const float* __restrict__ z, const float* __restrict__ emb,
    float* __restrict__ zq, float* __restrict__ loss,
    float* __restrict__ idxf, float invN)
{
    __shared__ short Bs_hi[BN * LDBS];
    __shared__ short Bs_lo[BN * LDBS];
    __shared__ float topk[2][BM][2];
    __shared__ int   rowIdx[BM];
    __shared__ int   ambList[BM];
    __shared__ int   ambCnt;
    __shared__ float zs[E_DIM];
    __shared__ float redV[8];
    __shared__ int   redI[8];

    const int tid  = threadIdx.x;
    const int lane = tid & 63;
    const int w    = tid >> 6;       // wave 0..7
    const int wm   = w >> 1;         // row group 0..3 (32 rows each)
    const int wn   = w & 1;          // col half 0..1 (64 cols each)
    const int l15  = lane & 15;
    const int l4   = lane >> 4;
    const int rb   = blockIdx.x * BM;

    // ---- A (z) fragments -> registers as bf16 hi/lo; z read ONCE ----
    bf16x8 a_hi[2][8], a_lo[2][8];
#pragma unroll
    for (int m = 0; m < 2; ++m) {
        const float* zp = &z[(size_t)(rb + wm * 32 + m * 16 + l15) * E_DIM + l4 * 8];
#pragma unroll
        for (int s = 0; s < 8; ++s) {
            const f32x4 x0 = *reinterpret_cast<const f32x4*>(&zp[s * 32]);
            const f32x4 x1 = *reinterpret_cast<const f32x4*>(&zp[s * 32 + 4]);
            bf16x8 h, l; short hh, ll;
#pragma unroll
            for (int j = 0; j < 4; ++j) { split2(x0[j], hh, ll); h[j]   = hh; l[j]   = ll; }
#pragma unroll
            for (int j = 0; j < 4; ++j) { split2(x1[j], hh, ll); h[4+j] = hh; l[4+j] = ll; }
            a_hi[m][s] = h; a_lo[m][s] = l;
        }
    }

    float k1[2][4], k2[2][4];
#pragma unroll
    for (int m = 0; m < 2; ++m)
#pragma unroll
        for (int j = 0; j < 4; ++j) { k1[m][j] = -3.0e38f; k2[m][j] = -3.0e38f; }

    for (int cn = 0; cn < NC; cn += BN) {
        f32x4 acc[2][4];
        const f32x4 zz = {0.f, 0.f, 0.f, 0.f};
#pragma unroll
        for (int m = 0; m < 2; ++m)
#pragma unroll
            for (int n = 0; n < 4; ++n) acc[m][n] = zz;

#pragma unroll
        for (int kk = 0; kk < 4; ++kk) {            // k chunks of 64
            __syncthreads();
            // stage B (emb) chunk as bf16 hi/lo
#pragma unroll
            for (int i = 0; i < 4; ++i) {
                const int q   = i * NT + tid;       // 2048 float4 quads
                const int row = q >> 4;
                const int c   = q & 15;
                const f32x4 b4 = *reinterpret_cast<const f32x4*>(
                    &emb[(size_t)(cn + row) * E_DIM + kk * 64 + c * 4]);
                bf16x4 hv, lv; short hh, ll;
#pragma unroll
                for (int j = 0; j < 4; ++j) { split2(b4[j], hh, ll); hv[j] = hh; lv[j] = ll; }
                *reinterpret_cast<bf16x4*>(&Bs_hi[row * LDBS + c * 4]) = hv;
                *reinterpret_cast<bf16x4*>(&Bs_lo[row * LDBS + c * 4]) = lv;
            }
            __syncthreads();
#pragma unroll
            for (int h = 0; h < 2; ++h) {           // two k=32 slices
                bf16x8 bh[4], bl[4];
#pragma unroll
                for (int n = 0; n < 4; ++n) {
                    const int off = (wn * 64 + n * 16 + l15) * LDBS + (h * 4 + l4) * 8;
                    bh[n] = *reinterpret_cast<const bf16x8*>(&Bs_hi[off]);
                    bl[n] = *reinterpret_cast<const bf16x8*>(&Bs_lo[off]);
                }
#pragma unroll
                for (int m = 0; m < 2; ++m) {
                    const bf16x8 ah = a_hi[m][kk * 2 + h];
                    const bf16x8 al = a_lo[m][kk * 2 + h];
#pragma unroll
                    for (int n = 0; n < 4; ++n) {
                        acc[m][n] = __builtin_amdgcn_mfma_f32_16x16x32_bf16(ah, bh[n], acc[m][n], 0, 0, 0);
                        acc[m][n] = __builtin_amdgcn_mfma_f32_16x16x32_bf16(ah, bl[n], acc[m][n], 0, 0, 0);
                        acc[m][n] = __builtin_amdgcn_mfma_f32_16x16x32_bf16(al, bh[n], acc[m][n], 0, 0, 0);
                    }
                }
            }
        }

        // fold tile into running top-2 mangled keys
        const int colbase = cn + wn * 64 + l15;
        unsigned il[4];
#pragma unroll
        for (int n = 0; n < 4; ++n) il[n] = (unsigned)(1023 - (colbase + n * 16));
#pragma unroll
        for (int m = 0; m < 2; ++m)
#pragma unroll
            for (int j = 0; j < 4; ++j) {
                const float a0 = acc[m][0][j], a1 = acc[m][1][j];
                const float a2 = acc[m][2][j], a3 = acc[m][3][j];
                const float q = fmaxf(fmaxf(a0, a1), fmaxf(a2, a3));
                if (q > k2[m][j]) {
                    float x, t;
                    x = mkey(a0, il[0]); t = fminf(k1[m][j], x);
                    k1[m][j] = fmaxf(k1[m][j], x); k2[m][j] = fmaxf(k2[m][j], t);
                    x = mkey(a1, il[1]); t = fminf(k1[m][j], x);
                    k1[m][j] = fmaxf(k1[m][j], x); k2[m][j] = fmaxf(k2[m][j], t);
                    x = mkey(a2, il[2]); t = fminf(k1[m][j], x);
                    k1[m][j] = fmaxf(k1[m][j], x); k2[m][j] = fmaxf(k2[m][j], t);
                    x = mkey(a3, il[3]); t = fminf(k1[m][j], x);
                    k1[m][j] = fmaxf(k1[m][j], x); k2[m][j] = fmaxf(k2[m][j], t);
                }
            }
    }

    // reduce top-2 across the 16 lanes sharing each row
#pragma unroll
    for (int m = 0; m < 2; ++m)
#pragma unroll
        for (int j = 0; j < 4; ++j) {
            float a = k1[m][j], b = k2[m][j];
#pragma unroll
            for (int s = 1; s < 16; s <<= 1) {
                const float oa = __shfl_xor(a, s, 64);
                const float ob = __shfl_xor(b, s, 64);
                const float t  = fminf(a, oa);
                a = fmaxf(a, oa);
                b = fmaxf(fmaxf(b, ob), t);
            }
            if (l15 == 0) {
                const int row = wm * 32 + m * 16 + l4 * 4 + j;
                topk[wn][row][0] = a;
                topk[wn][row][1] = b;
            }
        }
    if (tid == 0) ambCnt = 0;
    __syncthreads();

    if (tid < BM) {
        float a = topk[0][tid][0], b = topk[0][tid][1];
        const float oa = topk[1][tid][0], ob = topk[1][tid][1];
        const float t  = fminf(a, oa);
        a = fmaxf(a, oa);
        b = fmaxf(fmaxf(b, ob), t);
        const unsigned ub = __float_as_uint(a);
        rowIdx[tid] = 1023 - (int)(ub & 1023u);
        const float v1 = __uint_as_float(ub & 0xFFFFFC00u);
        const float v2 = __uint_as_float(__float_as_uint(b) & 0xFFFFFC00u);
        if (v1 - v2 <= MARGIN) {                 // ambiguous -> exact in-block rescan
            const int p = atomicAdd(&ambCnt, 1); // capacity == BM, cannot overflow
            ambList[p] = tid;
        }
    }
    __syncthreads();

    // exact f32 rescan of flagged rows (rare: ~0.5% of rows)
    const int nAmb = ambCnt;
    for (int ai = 0; ai < nAmb; ++ai) {
        const int row = ambList[ai];
        if (tid < 64)
            *reinterpret_cast<f32x4*>(&zs[tid * 4]) =
                *reinterpret_cast<const f32x4*>(&z[(size_t)(rb + row) * E_DIM + tid * 4]);
        __syncthreads();
        float best = -3.0e38f; int bidx = 0;
#pragma unroll
        for (int cc = 0; cc < 2; ++cc) {
            const int c = tid * 2 + cc;          // ascending within thread
            const float* ep = &emb[(size_t)c * E_DIM];
            float p = 0.f;
#pragma unroll 8
            for (int qd = 0; qd < 64; ++qd) {
                const f32x4 e4 = *reinterpret_cast<const f32x4*>(&ep[qd * 4]);
                const f32x4 z4 = *reinterpret_cast<const f32x4*>(&zs[qd * 4]);
                p = fmaf(z4[0], e4[0], p); p = fmaf(z4[1], e4[1], p);
                p = fmaf(z4[2], e4[2], p); p = fmaf(z4[3], e4[3], p);
            }
            if (p > best) { best = p; bidx = c; }
        }
#pragma unroll
        for (int s = 1; s < 64; s <<= 1) {
            const float ov = __shfl_xor(best, s, 64);
            const int   oi = __shfl_xor(bidx, s, 64);
            if (ov > best || (ov == best && oi < bidx)) { best = ov; bidx = oi; }
        }
        if (lane == 0) { redV[w] = best; redI[w] = bidx; }
        __syncthreads();
        if (tid == 0) {
            float bb = redV[0]; int bi = redI[0];
#pragma unroll
            for (int ww = 1; ww < 8; ++ww)
                if (redV[ww] > bb) { bb = redV[ww]; bi = redI[ww]; }
            rowIdx[row] = bi;                    // zq & idx both come from rowIdx
        }
        __syncthreads();
    }

    // epilogue: gather emb[idx] -> zq, SSE, idx output, loss atomics
    float sse = 0.f;
#pragma unroll
    for (int i = 0; i < 16; ++i) {
        const int f   = i * NT + tid;            // 8192 quads of the 128x256 tile
        const int row = f >> 6;
        const int kq  = f & 63;
        const int idx = rowIdx[row];
        const f32x4 e4 = *reinterpret_cast<const f32x4*>(&emb[(size_t)idx * E_DIM + kq * 4]);
        const f32x4 z4 = *reinterpret_cast<const f32x4*>(&z[(size_t)(rb + row) * E_DIM + kq * 4]);
        const float d0 = e4[0] - z4[0], d1 = e4[1] - z4[1];
        const float d2 = e4[2] - z4[2], d3 = e4[3] - z4[3];
        sse += d0 * d0 + d1 * d1 + d2 * d2 + d3 * d3;
        *reinterpret_cast<f32x4*>(&zq[(size_t)(rb + row) * E_DIM + kq * 4]) = e4;
    }
    if (tid < BM) idxf[rb + tid] = (float)rowIdx[tid];
#pragma unroll
    for (int s = 1; s < 64; s <<= 1) sse += __shfl_xor(sse, s, 64);
    if (lane == 0) redV[w] = sse;
    __syncthreads();
    if (tid == 0) {
        float t = 0.f;
#pragma unroll
        for (int ww = 0; ww < 8; ++ww) t += redV[ww];
        atomicAdd(&loss[0], t * invN);
        atomicAdd(&loss[1], 0.25f * t * invN);
    }
}

extern "C" void kernel_launch(void* const* d_in, const int* in_sizes, int n_in,
                              void* d_out, int out_size, void* d_ws, size_t ws_size,
                              hipStream_t stream) {
    const float* z   = (const float*)d_in[0];
    const float* emb = (const float*)d_in[1];
    const int zsz    = in_sizes[0];        // 33554432
    const int nrows  = zsz / E_DIM;        // 131072

    float* out  = (float*)d_out;
    float* zq   = out;                     // [nrows * E_DIM]
    float* loss = out + zsz;               // [2]
    float* idxf = out + zsz + 2;           // [nrows] as float values

    hipMemsetAsync(loss, 0, 2 * sizeof(float), stream);

    vq_kernel<<<dim3(nrows / BM), NT, 0, stream>>>(
        z, emb, zq, loss, idxf, 1.0f / ((float)nrows * (float)E_DIM));
}

// Round 5
// 632.030 us; speedup vs baseline: 1.5445x; 1.1909x over previous
//
#include <hip/hip_runtime.h>

#define E_DIM  256
#define NC     1024
#define BM     128
#define NT     512
#define MARGIN 0.02f

typedef short  bf16x4 __attribute__((ext_vector_type(4)));
typedef short  bf16x8 __attribute__((ext_vector_type(8)));
typedef float  f32x4  __attribute__((ext_vector_type(4)));

// split f32 into bf16 hi + bf16 lo (both round-to-nearest-even)
static __device__ __forceinline__ void split2(float x, short& hi, short& lo) {
    const unsigned u  = __float_as_uint(x);
    const unsigned hb = (u + 0x7FFFu + ((u >> 16) & 1u)) >> 16;
    hi = (short)hb;
    const float l = x - __uint_as_float(hb << 16);   // exact in f32
    const unsigned u2 = __float_as_uint(l);
    lo = (short)((u2 + 0x7FFFu + ((u2 >> 16) & 1u)) >> 16);
}

// value with low 10 mantissa bits <- (1023 - idx): fmax = value-compare with
// first-index tie-break for positive gaps; perturbation << MARGIN.
static __device__ __forceinline__ float mkey(float v, unsigned il) {
    return __uint_as_float((__float_as_uint(v) & 0xFFFFFC00u) | il);
}

// async 16B global -> LDS (wave-uniform LDS base + lane*16)
static __device__ __forceinline__ void gload16(const void* g, void* l) {
    __builtin_amdgcn_global_load_lds(
        (const __attribute__((address_space(1))) unsigned int*)g,
        (__attribute__((address_space(3))) unsigned int*)l, 16, 0, 0);
}

// ---- prep: emb (f32) -> per-chunk LDS images of bf16 hi/lo, XOR-swizzled ----
// d_ws layout: for gc = tile*4+chunk (32 chunks): 32KB image = [hi 16KB][lo 16KB]
// image[row*128 + x] (bytes) = data(row, x ^ ((row&7)<<4)); involution.
__global__ __launch_bounds__(256) void vq_prep(
    const float* __restrict__ emb, short* __restrict__ img)
{
    const int t     = blockIdx.x * 256 + threadIdx.x;  // 0..32767
    const int b     = t & 7;            // 16B group within row
    const int row   = (t >> 3) & 127;   // code row within tile
    const int chunk = (t >> 10) & 3;    // k chunk of 64
    const int tile  = t >> 12;          // 0..7
    const int cb    = (b << 4) ^ ((row & 7) << 4);   // logical col-byte start
    const int s0    = cb >> 1;                       // logical short start
    const float* src = &emb[(size_t)(tile * 128 + row) * E_DIM + chunk * 64 + s0];
    const f32x4 x0 = *reinterpret_cast<const f32x4*>(&src[0]);
    const f32x4 x1 = *reinterpret_cast<const f32x4*>(&src[4]);
    bf16x8 h, l; short hh, ll;
#pragma unroll
    for (int j = 0; j < 4; ++j) { split2(x0[j], hh, ll); h[j]     = hh; l[j]     = ll; }
#pragma unroll
    for (int j = 0; j < 4; ++j) { split2(x1[j], hh, ll); h[4 + j] = hh; l[4 + j] = ll; }
    const size_t base = (size_t)(tile * 4 + chunk) * 16384;   // shorts per 32KB chunk
    *reinterpret_cast<bf16x8*>(&img[base + row * 64 + b * 8])        = h;
    *reinterpret_cast<bf16x8*>(&img[base + 8192 + row * 64 + b * 8]) = l;
}

__global__ __launch_bounds__(NT, 2) void vq_kernel(
    const float* __restrict__ z, const float* __restrict__ emb,
    const short* __restrict__ img, float* __restrict__ zq,
    float* __restrict__ loss, float* __restrict__ idxf, float invN)
{
    __shared__ char  Bs[2][32768];
    __shared__ float topk[2][BM][2];
    __shared__ int   rowIdx[BM];
    __shared__ int   ambList[BM];
    __shared__ int   ambCnt;
    __shared__ float zs[E_DIM];
    __shared__ float redV[8];
    __shared__ int   redI[8];

    const int tid  = threadIdx.x;
    const int lane = tid & 63;
    const int w    = tid >> 6;       // wave 0..7
    const int wm   = w >> 1;         // row group 0..3 (32 rows each)
    const int wn   = w & 1;          // col half 0..1 (64 cols each)
    const int l15  = lane & 15;
    const int l4   = lane >> 4;
    const int rb   = blockIdx.x * BM;

    // prologue: stage chunk 0 into buf 0 (latency hides under A-conversion)
    {
        const char* g = (const char*)img;
#pragma unroll
        for (int q = 0; q < 4; ++q) {
            const int off = (q * 8 + w) * 1024;
            gload16(g + off + (lane << 4), &Bs[0][off]);
        }
    }

    // ---- A (z) fragments -> registers as bf16 hi/lo; z read ONCE ----
    bf16x8 a_hi[2][8], a_lo[2][8];
#pragma unroll
    for (int m = 0; m < 2; ++m) {
        const float* zp = &z[(size_t)(rb + wm * 32 + m * 16 + l15) * E_DIM + l4 * 8];
#pragma unroll
        for (int s = 0; s < 8; ++s) {
            const f32x4 x0 = *reinterpret_cast<const f32x4*>(&zp[s * 32]);
            const f32x4 x1 = *reinterpret_cast<const f32x4*>(&zp[s * 32 + 4]);
            bf16x8 h, l; short hh, ll;
#pragma unroll
            for (int j = 0; j < 4; ++j) { split2(x0[j], hh, ll); h[j]   = hh; l[j]   = ll; }
#pragma unroll
            for (int j = 0; j < 4; ++j) { split2(x1[j], hh, ll); h[4+j] = hh; l[4+j] = ll; }
            a_hi[m][s] = h; a_lo[m][s] = l;
        }
    }

    float k1[2][4], k2[2][4];
#pragma unroll
    for (int m = 0; m < 2; ++m)
#pragma unroll
        for (int j = 0; j < 4; ++j) { k1[m][j] = -3.0e38f; k2[m][j] = -3.0e38f; }

    __syncthreads();   // chunk 0 staged (full vmcnt drain at barrier)

    for (int tile = 0; tile < 8; ++tile) {
        f32x4 acc[2][4];
        const f32x4 zz = {0.f, 0.f, 0.f, 0.f};
#pragma unroll
        for (int m = 0; m < 2; ++m)
#pragma unroll
            for (int n = 0; n < 4; ++n) acc[m][n] = zz;

#pragma unroll
        for (int kk = 0; kk < 4; ++kk) {
            const int gc  = tile * 4 + kk;
            // stage next chunk into the other buffer (async, overlaps MFMA below)
            const int sgc = (gc < 31) ? gc + 1 : 31;   // final re-stage is harmless
            {
                const char* g = (const char*)img + (size_t)sgc * 32768;
                char* const db = Bs[(kk + 1) & 1];
#pragma unroll
                for (int q = 0; q < 4; ++q) {
                    const int off = (q * 8 + w) * 1024;
                    gload16(g + off + (lane << 4), &db[off]);
                }
            }
            // compute current chunk
            const char* bc = Bs[kk & 1];
#pragma unroll
            for (int h = 0; h < 2; ++h) {
                bf16x8 bh[4], bl[4];
#pragma unroll
                for (int n = 0; n < 4; ++n) {
                    const int row = wn * 64 + n * 16 + l15;
                    const int off = row * 128 + (((h * 4 + l4) << 4) ^ ((row & 7) << 4));
                    bh[n] = *reinterpret_cast<const bf16x8*>(&bc[off]);
                    bl[n] = *reinterpret_cast<const bf16x8*>(&bc[16384 + off]);
                }
#pragma unroll
                for (int m = 0; m < 2; ++m) {
                    const bf16x8 ah = a_hi[m][kk * 2 + h];
                    const bf16x8 al = a_lo[m][kk * 2 + h];
#pragma unroll
                    for (int n = 0; n < 4; ++n) {
                        acc[m][n] = __builtin_amdgcn_mfma_f32_16x16x32_bf16(ah, bh[n], acc[m][n], 0, 0, 0);
                        acc[m][n] = __builtin_amdgcn_mfma_f32_16x16x32_bf16(ah, bl[n], acc[m][n], 0, 0, 0);
                        acc[m][n] = __builtin_amdgcn_mfma_f32_16x16x32_bf16(al, bh[n], acc[m][n], 0, 0, 0);
                    }
                }
            }
            __syncthreads();
        }

        // fold tile into running top-2 mangled keys (register-only)
        const int colbase = tile * 128 + wn * 64 + l15;
        unsigned il[4];
#pragma unroll
        for (int n = 0; n < 4; ++n) il[n] = (unsigned)(1023 - (colbase + n * 16));
#pragma unroll
        for (int m = 0; m < 2; ++m)
#pragma unroll
            for (int j = 0; j < 4; ++j) {
                const float a0 = acc[m][0][j], a1 = acc[m][1][j];
                const float a2 = acc[m][2][j], a3 = acc[m][3][j];
                const float q = fmaxf(fmaxf(a0, a1), fmaxf(a2, a3));
                if (q > k2[m][j]) {
                    float x, t;
                    x = mkey(a0, il[0]); t = fminf(k1[m][j], x);
                    k1[m][j] = fmaxf(k1[m][j], x); k2[m][j] = fmaxf(k2[m][j], t);
                    x = mkey(a1, il[1]); t = fminf(k1[m][j], x);
                    k1[m][j] = fmaxf(k1[m][j], x); k2[m][j] = fmaxf(k2[m][j], t);
                    x = mkey(a2, il[2]); t = fminf(k1[m][j], x);
                    k1[m][j] = fmaxf(k1[m][j], x); k2[m][j] = fmaxf(k2[m][j], t);
                    x = mkey(a3, il[3]); t = fminf(k1[m][j], x);
                    k1[m][j] = fmaxf(k1[m][j], x); k2[m][j] = fmaxf(k2[m][j], t);
                }
            }
    }

    // reduce top-2 across the 16 lanes sharing each row
#pragma unroll
    for (int m = 0; m < 2; ++m)
#pragma unroll
        for (int j = 0; j < 4; ++j) {
            float a = k1[m][j], b = k2[m][j];
#pragma unroll
            for (int s = 1; s < 16; s <<= 1) {
                const float oa = __shfl_xor(a, s, 64);
                const float ob = __shfl_xor(b, s, 64);
                const float t  = fminf(a, oa);
                a = fmaxf(a, oa);
                b = fmaxf(fmaxf(b, ob), t);
            }
            if (l15 == 0) {
                const int row = wm * 32 + m * 16 + l4 * 4 + j;
                topk[wn][row][0] = a;
                topk[wn][row][1] = b;
            }
        }
    if (tid == 0) ambCnt = 0;
    __syncthreads();

    if (tid < BM) {
        float a = topk[0][tid][0], b = topk[0][tid][1];
        const float oa = topk[1][tid][0], ob = topk[1][tid][1];
        const float t  = fminf(a, oa);
        a = fmaxf(a, oa);
        b = fmaxf(fmaxf(b, ob), t);
        const unsigned ub = __float_as_uint(a);
        rowIdx[tid] = 1023 - (int)(ub & 1023u);
        const float v1 = __uint_as_float(ub & 0xFFFFFC00u);
        const float v2 = __uint_as_float(__float_as_uint(b) & 0xFFFFFC00u);
        if (v1 - v2 <= MARGIN) {                 // ambiguous -> exact in-block rescan
            const int p = atomicAdd(&ambCnt, 1); // capacity == BM, cannot overflow
            ambList[p] = tid;
        }
    }
    __syncthreads();

    // exact f32 rescan of flagged rows (rare)
    const int nAmb = ambCnt;
    for (int ai = 0; ai < nAmb; ++ai) {
        const int row = ambList[ai];
        if (tid < 64)
            *reinterpret_cast<f32x4*>(&zs[tid * 4]) =
                *reinterpret_cast<const f32x4*>(&z[(size_t)(rb + row) * E_DIM + tid * 4]);
        __syncthreads();
        float best = -3.0e38f; int bidx = 0;
#pragma unroll
        for (int cc = 0; cc < 2; ++cc) {
            const int c = tid * 2 + cc;          // ascending within thread
            const float* ep = &emb[(size_t)c * E_DIM];
            float p = 0.f;
#pragma unroll 8
            for (int qd = 0; qd < 64; ++qd) {
                const f32x4 e4 = *reinterpret_cast<const f32x4*>(&ep[qd * 4]);
                const f32x4 z4 = *reinterpret_cast<const f32x4*>(&zs[qd * 4]);
                p = fmaf(z4[0], e4[0], p); p = fmaf(z4[1], e4[1], p);
                p = fmaf(z4[2], e4[2], p); p = fmaf(z4[3], e4[3], p);
            }
            if (p > best) { best = p; bidx = c; }
        }
#pragma unroll
        for (int s = 1; s < 64; s <<= 1) {
            const float ov = __shfl_xor(best, s, 64);
            const int   oi = __shfl_xor(bidx, s, 64);
            if (ov > best || (ov == best && oi < bidx)) { best = ov; bidx = oi; }
        }
        if (lane == 0) { redV[w] = best; redI[w] = bidx; }
        __syncthreads();
        if (tid == 0) {
            float bb = redV[0]; int bi = redI[0];
#pragma unroll
            for (int ww = 1; ww < 8; ++ww)
                if (redV[ww] > bb) { bb = redV[ww]; bi = redI[ww]; }
            rowIdx[row] = bi;                    // zq & idx both come from rowIdx
        }
        __syncthreads();
    }

    // epilogue: gather emb[idx] -> zq, SSE, idx output, loss atomics
    float sse = 0.f;
#pragma unroll
    for (int i = 0; i < 16; ++i) {
        const int f   = i * NT + tid;            // 8192 quads of the 128x256 tile
        const int row = f >> 6;
        const int kq  = f & 63;
        const int idx = rowIdx[row];
        const f32x4 e4 = *reinterpret_cast<const f32x4*>(&emb[(size_t)idx * E_DIM + kq * 4]);
        const f32x4 z4 = *reinterpret_cast<const f32x4*>(&z[(size_t)(rb + row) * E_DIM + kq * 4]);
        const float d0 = e4[0] - z4[0], d1 = e4[1] - z4[1];
        const float d2 = e4[2] - z4[2], d3 = e4[3] - z4[3];
        sse += d0 * d0 + d1 * d1 + d2 * d2 + d3 * d3;
        *reinterpret_cast<f32x4*>(&zq[(size_t)(rb + row) * E_DIM + kq * 4]) = e4;
    }
    if (tid < BM) idxf[rb + tid] = (float)rowIdx[tid];
#pragma unroll
    for (int s = 1; s < 64; s <<= 1) sse += __shfl_xor(sse, s, 64);
    if (lane == 0) redV[w] = sse;
    __syncthreads();
    if (tid == 0) {
        float t = 0.f;
#pragma unroll
        for (int ww = 0; ww < 8; ++ww) t += redV[ww];
        atomicAdd(&loss[0], t * invN);
        atomicAdd(&loss[1], 0.25f * t * invN);
    }
}

extern "C" void kernel_launch(void* const* d_in, const int* in_sizes, int n_in,
                              void* d_out, int out_size, void* d_ws, size_t ws_size,
                              hipStream_t stream) {
    const float* z   = (const float*)d_in[0];
    const float* emb = (const float*)d_in[1];
    const int zsz    = in_sizes[0];        // 33554432
    const int nrows  = zsz / E_DIM;        // 131072

    float* out  = (float*)d_out;
    float* zq   = out;                     // [nrows * E_DIM]
    float* loss = out + zsz;               // [2]
    float* idxf = out + zsz + 2;           // [nrows] as float values

    short* img = (short*)d_ws;             // 1 MB of bf16 hi/lo chunk images

    hipMemsetAsync(loss, 0, 2 * sizeof(float), stream);

    vq_prep<<<dim3(128), 256, 0, stream>>>(emb, img);
    vq_kernel<<<dim3(nrows / BM), NT, 0, stream>>>(
        z, emb, img, zq, loss, idxf, 1.0f / ((float)nrows * (float)E_DIM));
}